// Round 18
// baseline (4543.245 us; speedup 1.0000x reference)
//
#include <hip/hip_runtime.h>

// ============================================================================
// CapsuleNet forward. Round 18 (base = r16 = 1017 us verified):
//  - fused_conv: r6 structure VERBATIM but block = 1 IMAGE, grid = 512.
//    r17 post-mortem: grid 256 = 1 block/CU exactly -> cross-block overlap
//    never possible. Now: LDS ~59KB, 512 blocks -> 2 blocks/CU; block A's
//    conv1 (VALU) overlaps block B's MFMA (separate pipes). M = 36 -> 3
//    m-tiles (48 rows, 33% pad = +20% MFMA), acc[3][4] = 48 VGPR.
//  - repack_b (CHUNK=16, 656 ktiles) + pass-0 GEMM + RG=4 routing: r16
//    verbatim.
// ============================================================================

#define N_IMG 512
#define RG 4  // images per routing block

// fused_conv LDS geometry (bytes): 4 A-arrays (hi/lo x ci-half) of 408
// slots x 16B, then stg/img/w1l/b1l. mrg (49,152B) and sq (36,864B) alias
// the front of smem after the K loop.
#define ARRS 6528                  // 408 slots x 16B
#define STG_OFF (4 * ARRS)         // 26112: stg [16][404] f32 (25856)
#define IMG_OFF (STG_OFF + 25856)  // 51968: img [784] f32 (3136)
#define W1L_OFF (IMG_OFF + 3136)   // 55104: w1l [16*81] f32 (5184)
#define B1L_OFF (W1L_OFF + 5184)   // 60288: b1l [16] f32
#define SMEM_SZ (B1L_OFF + 64)     // 60352

typedef __attribute__((ext_vector_type(8))) short bf16x8;
typedef __attribute__((ext_vector_type(4))) float f32x4;
typedef __attribute__((ext_vector_type(4))) unsigned int u32x4;

__device__ __forceinline__ unsigned short f2bf(float v) {
  unsigned int uu = __float_as_uint(v);
  uu += 0x7FFF + ((uu >> 16) & 1);
  return (unsigned short)(uu >> 16);
}
__device__ __forceinline__ float bf2f(unsigned short h) {
  return __uint_as_float(((unsigned int)h) << 16);
}
__device__ __forceinline__ int swz16(int row) {  // byte offset of 16B A-row
  return (row ^ ((row >> 3) & 7)) << 4;
}

// ---------------------------------------------------------------------------
// repack conv2 weights w2[256co][256ci][81rs] -> B-fragment order (hi/lo):
// Bp[n 16][ktile 656][lane 64][8], ktile = c*41+tt, rs = 2tt+lh padded to 82.
// (r16 verbatim)
// ---------------------------------------------------------------------------
__global__ __launch_bounds__(256) void repack_b_kernel(
    const float* __restrict__ w2, unsigned short* __restrict__ bph,
    unsigned short* __restrict__ bpl) {
  __shared__ float slab[82 * 16 * 17];  // [rs][co][ci pad 17]
  const int n = blockIdx.x, c = blockIdx.y;
  const int tid = threadIdx.x;
  for (int e = tid; e < 81 * 256; e += 256) {
    const int row = e / 81;
    const int rs = e - row * 81;
    const int co = row >> 4, ci = row & 15;
    slab[(rs * 16 + co) * 17 + ci] =
        w2[((size_t)(n * 16 + co) * 256 + c * 16 + ci) * 81 + rs];
  }
  __syncthreads();
  const int lane = tid & 63;
  const int l15 = lane & 15;
  const int lh = lane >> 5;
  const int cio8 = ((lane >> 4) & 1) * 8;
  for (int tt = tid >> 6; tt < 41; tt += 4) {
    const int rs = 2 * tt + lh;
    unsigned int hw[4], lw[4];
#pragma unroll
    for (int jp = 0; jp < 4; ++jp) {
      unsigned short h2[2], l2[2];
#pragma unroll
      for (int e = 0; e < 2; ++e) {
        const int j = jp * 2 + e;
        float v = (rs < 81) ? slab[(rs * 16 + l15) * 17 + cio8 + j] : 0.0f;
        unsigned short hh = f2bf(v);
        h2[e] = hh;
        l2[e] = f2bf(v - bf2f(hh));
      }
      hw[jp] = (unsigned int)h2[0] | ((unsigned int)h2[1] << 16);
      lw[jp] = (unsigned int)l2[0] | ((unsigned int)l2[1] << 16);
    }
    const size_t off = (((size_t)n * 656 + c * 41 + tt) * 64 + lane) * 8;
    *(u32x4*)(bph + off) = (u32x4){hw[0], hw[1], hw[2], hw[3]};
    *(u32x4*)(bpl + off) = (u32x4){lw[0], lw[1], lw[2], lw[3]};
  }
}

// ---------------------------------------------------------------------------
// transpose caps_w [1152][8][160] -> fp32 cw_t [1152][160][8].
// ---------------------------------------------------------------------------
__global__ __launch_bounds__(160) void repack_cw_kernel(
    const float* __restrict__ cw, float* __restrict__ cwt) {
  __shared__ float t[8][160];
  const int i = blockIdx.x;
  const int od = threadIdx.x;
#pragma unroll
  for (int k = 0; k < 8; ++k) t[k][od] = cw[((size_t)i * 8 + k) * 160 + od];
  __syncthreads();
  float4 o0 = {t[0][od], t[1][od], t[2][od], t[3][od]};
  float4 o1 = {t[4][od], t[5][od], t[6][od], t[7][od]};
  float4* dst = (float4*)(cwt + ((size_t)i * 160 + od) * 8);
  dst[0] = o0;
  dst[1] = o1;
}

// ---------------------------------------------------------------------------
// c0 = softmax(b_prior) per capsule (image-independent).
// ---------------------------------------------------------------------------
__global__ __launch_bounds__(256) void c0_kernel(const float* __restrict__ bp,
                                                 float* __restrict__ c0b) {
  const int i = blockIdx.x * 256 + threadIdx.x;
  if (i >= 1152) return;
  float b[10];
  float m = -1e30f;
#pragma unroll
  for (int o = 0; o < 10; ++o) {
    b[o] = bp[i * 10 + o];
    m = fmaxf(m, b[o]);
  }
  float sum = 0.0f;
#pragma unroll
  for (int o = 0; o < 10; ++o) {
    b[o] = __expf(b[o] - m);
    sum += b[o];
  }
  const float inv = 1.0f / sum;
#pragma unroll
  for (int o = 0; o < 10; ++o) c0b[i * 10 + o] = b[o] * inv;
}

// ---------------------------------------------------------------------------
// Pass-0 GEMM (r12 verbatim): s0 partials over 36 K-splits.
// ---------------------------------------------------------------------------
__global__ __launch_bounds__(256) void gemm_s0_kernel(
    const float* __restrict__ u, const float* __restrict__ cw,
    const float* __restrict__ c0b, float* __restrict__ s0p) {
  __shared__ float a_l[64 * 257];
  __shared__ float b_l[64 * 160];
  __shared__ float c0_l[320];
  const int mt = blockIdx.x;   // 0..7
  const int ks = blockIdx.y;   // 0..35
  const int m0 = mt * 64;
  const int tid = threadIdx.x;
  const int mb = tid >> 4;
  const int ob = (tid & 15) * 10;

  for (int i = tid; i < 320; i += 256) c0_l[i] = c0b[(ks * 32) * 10 + i];
  for (int idx = tid; idx < 16384; idx += 256) {
    const int m = idx >> 8, kk = idx & 255;
    a_l[m * 257 + kk] = u[(size_t)(m0 + m) * 9216 + ks * 256 + kk];
  }

  float acc[4][10];
#pragma unroll
  for (int r = 0; r < 4; ++r)
#pragma unroll
    for (int c = 0; c < 10; ++c) acc[r][c] = 0.0f;

#pragma unroll 1
  for (int kc = 0; kc < 4; ++kc) {
    __syncthreads();
    for (int idx = tid; idx < 10240; idx += 256) {
      const int kk = idx / 160, od = idx - kk * 160;
      const int kg = kc * 64 + kk;
      b_l[kk * 160 + od] = cw[((size_t)ks * 256 + kg) * 160 + od] *
                           c0_l[(kg >> 3) * 10 + (od >> 4)];
    }
    __syncthreads();
#pragma unroll 4
    for (int kk = 0; kk < 64; ++kk) {
      float a4[4];
#pragma unroll
      for (int r = 0; r < 4; ++r)
        a4[r] = a_l[(mb * 4 + r) * 257 + kc * 64 + kk];
      const float* bp_ = &b_l[kk * 160 + ob];
#pragma unroll
      for (int c = 0; c < 10; ++c) {
        const float bv = bp_[c];
#pragma unroll
        for (int r = 0; r < 4; ++r) acc[r][c] = fmaf(a4[r], bv, acc[r][c]);
      }
    }
  }

#pragma unroll
  for (int r = 0; r < 4; ++r) {
#pragma unroll
    for (int c = 0; c < 10; ++c) {
      s0p[((size_t)ks * N_IMG + m0 + mb * 4 + r) * 160 + ob + c] = acc[r][c];
    }
  }
}

// ---------------------------------------------------------------------------
// conv1 half-row worker (round-6): 10 outputs at ox' = H*10 + (0..9).
// ---------------------------------------------------------------------------
template <int H>
__device__ __forceinline__ void conv1_half(const float* __restrict__ ib,
                                           const float* __restrict__ w1l,
                                           float* __restrict__ stg, int ch,
                                           int oy, float bv1) {
  float a[10];
#pragma unroll
  for (int ox = 0; ox < 10; ++ox) a[ox] = bv1;
#pragma unroll
  for (int r = 0; r < 9; ++r) {
    float row[20];
    const float4* rp = (const float4*)&ib[(oy + r) * 28 + H * 8];
#pragma unroll
    for (int q = 0; q < 5; ++q) {
      float4 v4 = rp[q];
      row[4 * q + 0] = v4.x; row[4 * q + 1] = v4.y;
      row[4 * q + 2] = v4.z; row[4 * q + 3] = v4.w;
    }
#pragma unroll
    for (int s = 0; s < 9; ++s) {
      const float wval = w1l[ch * 81 + r * 9 + s];
#pragma unroll
      for (int ox = 0; ox < 10; ++ox)
        a[ox] = fmaf(row[ox + s + 2 * H], wval, a[ox]);
    }
  }
  float2* dst = (float2*)&stg[oy * 20 + H * 10];
#pragma unroll
  for (int q = 0; q < 5; ++q) {
    float2 v2;
    v2.x = fmaxf(a[2 * q + 0], 0.0f);
    v2.y = fmaxf(a[2 * q + 1], 0.0f);
    dst[q] = v2;
  }
}

// ---------------------------------------------------------------------------
// Fused conv1 -> hi/lo A (swizzled) -> MFMA conv2 (k-split, depth-2 B
// prefetch) -> squash.  r6 structure, block = 1 IMAGE (grid 512 -> 2/CU).
// M = 36 rows -> 3 m-tiles (48, pad rows -> zero slot 402 = swz(400)).
// ---------------------------------------------------------------------------
__global__ __launch_bounds__(512, 4) void fused_conv_kernel(
    const float* __restrict__ x, const float* __restrict__ w1,
    const float* __restrict__ b1, const unsigned short* __restrict__ bph,
    const unsigned short* __restrict__ bpl, const float* __restrict__ b2,
    float* __restrict__ u) {
  __shared__ __align__(16) char smem[SMEM_SZ];
  float* stg = (float*)(smem + STG_OFF);  // [16][404]
  float* img = (float*)(smem + IMG_OFF);  // [784]
  float* w1l = (float*)(smem + W1L_OFF);  // [16*81]
  float* b1l = (float*)(smem + B1L_OFF);  // [16]
  float* mrg = (float*)smem;              // 49,152B alias
  float* sq = (float*)smem;               // 36,864B alias

  const int b = blockIdx.x;  // image
  const int tid = threadIdx.x;
  const int wid = tid >> 6;
  const int g = wid & 3;
  const int kpar = wid >> 2;
  const int lane = tid & 63;
  const int l15 = lane & 15;
  const int lq4 = lane >> 4;
  const int lqb = lq4 & 1;
  const int lh = lane >> 5;

  int rowb[3];
  bool okm[3];
#pragma unroll
  for (int mt = 0; mt < 3; ++mt) {
    const int m = mt * 16 + l15;
    okm[mt] = (m < 36);
    const int mm = okm[mt] ? m : 0;
    const int oy = mm / 6, ox = mm - 6 * oy;
    rowb[mt] = 40 * oy + 2 * ox;
  }

  for (int i = tid; i < 784; i += 512) img[i] = x[b * 784 + i];
  if (tid < 16) {  // zero pad-slot 402 (= swz(400)) in all 4 arrays
    *(int*)(smem + (tid >> 2) * ARRS + 402 * 16 + (tid & 3) * 4) = 0;
  }

  f32x4 acc[3][4];
#pragma unroll
  for (int mt = 0; mt < 3; ++mt)
#pragma unroll
    for (int nn = 0; nn < 4; ++nn) acc[mt][nn] = (f32x4){0.f, 0.f, 0.f, 0.f};

  const char* hbase = smem + lqb * ARRS;
  const char* lbase = smem + 2 * ARRS + lqb * ARRS;
  const int tt0 = kpar ? 21 : 0;
  const int tt1 = kpar ? 41 : 21;
  const int nk = tt1 - tt0;

#define MFMA_STEP(CBH, CBL, J, DOPF)                                       \
  {                                                                        \
    const int rs_ = 2 * (tt0 + (J)) + lh;                                  \
    const int r_ = (rs_ * 57) >> 9;                                        \
    const int s_ = rs_ - 9 * r_;                                           \
    const int rs20_ = 20 * r_ + s_;                                        \
    const bool okrs_ = (rs_ <= 80);                                        \
    bf16x8 ah[3], al[3];                                                   \
    _Pragma("unroll") for (int mt = 0; mt < 3; ++mt) {                     \
      const int row_ = (okm[mt] && okrs_) ? (rowb[mt] + rs20_) : 400;      \
      const int ad_ = swz16(row_);                                         \
      ah[mt] = *(const bf16x8*)(hbase + ad_);                              \
      al[mt] = *(const bf16x8*)(lbase + ad_);                              \
    }                                                                      \
    _Pragma("unroll") for (int mt = 0; mt < 3; ++mt) {                     \
      _Pragma("unroll") for (int nn = 0; nn < 4; ++nn) {                   \
        acc[mt][nn] = __builtin_amdgcn_mfma_f32_16x16x32_bf16(             \
            al[mt], CBH[nn], acc[mt][nn], 0, 0, 0);                        \
        acc[mt][nn] = __builtin_amdgcn_mfma_f32_16x16x32_bf16(             \
            ah[mt], CBL[nn], acc[mt][nn], 0, 0, 0);                        \
        acc[mt][nn] = __builtin_amdgcn_mfma_f32_16x16x32_bf16(             \
            ah[mt], CBH[nn], acc[mt][nn], 0, 0, 0);                        \
      }                                                                    \
    }                                                                      \
    if ((DOPF) && (J) + 2 < nk) {                                          \
      _Pragma("unroll") for (int nn = 0; nn < 4; ++nn) {                   \
        CBH[nn] = *(const bf16x8*)(pb[nn] + (size_t)((J) + 2) * 512);      \
        CBL[nn] = *(const bf16x8*)(pl[nn] + (size_t)((J) + 2) * 512);      \
      }                                                                    \
    }                                                                      \
  }

#pragma unroll 1
  for (int c = 0; c < 16; ++c) {
    const unsigned short* pb[4];
    const unsigned short* pl[4];
#pragma unroll
    for (int nn = 0; nn < 4; ++nn) {
      const size_t base =
          ((size_t)(g * 4 + nn) * 656 + c * 41 + tt0) * 512 + lane * 8;
      pb[nn] = bph + base;
      pl[nn] = bpl + base;
    }
    bf16x8 cbh0[4], cbl0[4], cbh1[4], cbl1[4];
#pragma unroll
    for (int nn = 0; nn < 4; ++nn) {
      cbh0[nn] = *(const bf16x8*)(pb[nn]);
      cbl0[nn] = *(const bf16x8*)(pl[nn]);
      cbh1[nn] = *(const bf16x8*)(pb[nn] + 512);
      cbl1[nn] = *(const bf16x8*)(pl[nn] + 512);
    }

    __syncthreads();  // prev chunk's MFMA A-reads + w1l reads done
    for (int i = tid; i < 1296; i += 512) w1l[i] = w1[c * 1296 + i];
    if (tid < 16) b1l[tid] = b1[c * 16 + tid];
    __syncthreads();

    // conv1: 640 tasks = half(2) x oy(20) x ch(16)
    for (int t = tid; t < 640; t += 512) {
      const int half = (t >= 320) ? 1 : 0;
      const int r2 = t - half * 320;
      const int ch = r2 & 15;
      const int oy = r2 >> 4;
      float* sb = &stg[ch * 404];
      const float bv1 = b1l[ch];
      if (half == 0)
        conv1_half<0>(img, w1l, sb, ch, oy, bv1);
      else
        conv1_half<1>(img, w1l, sb, ch, oy, bv1);
    }
    __syncthreads();

    // transpose stg -> swizzled A arrays (t == row = pos)
    for (int t = tid; t < 400; t += 512) {
      const int ad = swz16(t);
      unsigned int hw[8], lw[8];
#pragma unroll
      for (int jp = 0; jp < 8; ++jp) {
        unsigned short h2[2], l2[2];
#pragma unroll
        for (int e = 0; e < 2; ++e) {
          const float v = stg[(jp * 2 + e) * 404 + t];
          const unsigned short hh = f2bf(v);
          h2[e] = hh;
          l2[e] = f2bf(v - bf2f(hh));
        }
        hw[jp] = (unsigned int)h2[0] | ((unsigned int)h2[1] << 16);
        lw[jp] = (unsigned int)l2[0] | ((unsigned int)l2[1] << 16);
      }
      *(u32x4*)(smem + ad) = (u32x4){hw[0], hw[1], hw[2], hw[3]};
      *(u32x4*)(smem + ARRS + ad) = (u32x4){hw[4], hw[5], hw[6], hw[7]};
      *(u32x4*)(smem + 2 * ARRS + ad) = (u32x4){lw[0], lw[1], lw[2], lw[3]};
      *(u32x4*)(smem + 3 * ARRS + ad) = (u32x4){lw[4], lw[5], lw[6], lw[7]};
    }
    __syncthreads();

    int j = 0;
#pragma unroll 1
    for (; j + 1 < nk; j += 2) {
      MFMA_STEP(cbh0, cbl0, j, 1);
      MFMA_STEP(cbh1, cbl1, j + 1, 1);
    }
    if (j < nk) MFMA_STEP(cbh0, cbl0, j, 0);
  }
#undef MFMA_STEP

  // merge k-halves, bias, store sq, squash
  __syncthreads();
  if (kpar == 1) {
#pragma unroll
    for (int mt = 0; mt < 3; ++mt)
#pragma unroll
      for (int nn = 0; nn < 4; ++nn)
        *(f32x4*)(mrg + ((((g * 3 + mt) * 4 + nn) * 64 + lane) << 2)) =
            acc[mt][nn];
  }
  __syncthreads();
  if (kpar == 0) {
#pragma unroll
    for (int mt = 0; mt < 3; ++mt)
#pragma unroll
      for (int nn = 0; nn < 4; ++nn)
        acc[mt][nn] +=
            *(const f32x4*)(mrg + ((((g * 3 + mt) * 4 + nn) * 64 + lane) << 2));
  }
  __syncthreads();
  if (kpar == 0) {
    float b2v[4];
#pragma unroll
    for (int nn = 0; nn < 4; ++nn) b2v[nn] = b2[(g * 4 + nn) * 16 + l15];
#pragma unroll
    for (int mt = 0; mt < 3; ++mt) {
#pragma unroll
      for (int i = 0; i < 4; ++i) {
        const int m = mt * 16 + lq4 * 4 + i;
        if (m < 36) {
#pragma unroll
          for (int nn = 0; nn < 4; ++nn) {
            sq[((g * 4 + nn) * 16 + l15) * 36 + m] = acc[mt][nn][i] + b2v[nn];
          }
        }
      }
    }
  }
  __syncthreads();

  for (int i = tid; i < 1152; i += 512) {
    const int gg = i / 36, yx = i - 36 * gg;
    float vals[8];
    float lensq = 0.0f;
#pragma unroll
    for (int d = 0; d < 8; ++d) {
      vals[d] = sq[(gg * 8 + d) * 36 + yx];
      lensq = fmaf(vals[d], vals[d], lensq);
    }
    const float len = sqrtf(lensq);
    const float scale = lensq / (1.0f + lensq) / len;
    float4* dst = (float4*)(u + ((size_t)b * 1152 + i) * 8);
    float4 lo4, hi4;
    lo4.x = vals[0] * scale; lo4.y = vals[1] * scale;
    lo4.z = vals[2] * scale; lo4.w = vals[3] * scale;
    hi4.x = vals[4] * scale; hi4.y = vals[5] * scale;
    hi4.z = vals[6] * scale; hi4.w = vals[7] * scale;
    dst[0] = lo4; dst[1] = hi4;
  }
}

// ---------------------------------------------------------------------------
// routing pass A (passes 1-3, r16 verbatim): 4 images/block, 32-cap chunk as
// 2x16 subchunks; each cwt read serves 4 images (L2 traffic /4).
// ---------------------------------------------------------------------------
__global__ __launch_bounds__(256) void routing_a_kernel(
    const float* __restrict__ u, const float* __restrict__ cwt,
    const float* __restrict__ b_prior, const float* __restrict__ vsum,
    float* __restrict__ s_part) {
  __shared__ float u_l[RG * 16 * 8];
  __shared__ float uhat[RG][16][161];
  __shared__ float v_l[RG * 160];
  __shared__ float bp_l[32 * 10];
  __shared__ float c_l[RG * 16 * 10];
  __shared__ float s_acc[RG * 160];

  const int gb = blockIdx.x;  // image group (4 images)
  const int ch = blockIdx.y;  // 32-cap chunk (0..35)
  const int cap0 = ch * 32;
  const int b0 = gb * RG;
  const int tid = threadIdx.x;

  for (int i = tid; i < RG * 160; i += 256) {
    const int g = i / 160, od = i - g * 160;
    v_l[i] = vsum[(b0 + g) * 160 + od];
    s_acc[i] = 0.0f;
  }
  for (int i = tid; i < 320; i += 256) bp_l[i] = b_prior[cap0 * 10 + i];

#pragma unroll 1
  for (int cc = 0; cc < 2; ++cc) {
    const int c16 = cap0 + cc * 16;
    __syncthreads();
    for (int i = tid; i < RG * 128; i += 256) {
      const int g = i >> 7, off = i & 127;
      u_l[g * 128 + off] = u[((size_t)(b0 + g) * 1152 + c16) * 8 + off];
    }
    __syncthreads();

    for (int e = tid; e < 2560; e += 256) {
      const int i = e / 160, od = e - i * 160;
      const float4* wp =
          (const float4*)(cwt + ((size_t)(c16 + i) * 160 + od) * 8);
      const float4 wa = wp[0], wb = wp[1];
#pragma unroll
      for (int g = 0; g < RG; ++g) {
        const float* up = &u_l[(g * 16 + i) * 8];
        float a = up[0] * wa.x;
        a = fmaf(up[1], wa.y, a);
        a = fmaf(up[2], wa.z, a);
        a = fmaf(up[3], wa.w, a);
        a = fmaf(up[4], wb.x, a);
        a = fmaf(up[5], wb.y, a);
        a = fmaf(up[6], wb.z, a);
        a = fmaf(up[7], wb.w, a);
        uhat[g][i][od] = a;
      }
    }
    __syncthreads();

    for (int e = tid; e < RG * 160; e += 256) {
      const int g = e / 160;
      const int r = e - g * 160;
      const int i = r / 10, o = r - i * 10;
      float agg = 0.0f;
#pragma unroll
      for (int d = 0; d < 16; ++d)
        agg = fmaf(uhat[g][i][o * 16 + d], v_l[g * 160 + o * 16 + d], agg);
      c_l[e] = bp_l[(cc * 16 + i) * 10 + o] + agg;
    }
    __syncthreads();

    if (tid < RG * 16) {
      const int g = tid >> 4, i = tid & 15;
      float bb[10];
      float m = -1e30f;
#pragma unroll
      for (int o = 0; o < 10; ++o) {
        bb[o] = c_l[(g * 16 + i) * 10 + o];
        m = fmaxf(m, bb[o]);
      }
      float sum = 0.0f;
#pragma unroll
      for (int o = 0; o < 10; ++o) {
        bb[o] = __expf(bb[o] - m);
        sum += bb[o];
      }
      const float inv = 1.0f / sum;
#pragma unroll
      for (int o = 0; o < 10; ++o) c_l[(g * 16 + i) * 10 + o] = bb[o] * inv;
    }
    __syncthreads();

    for (int e = tid; e < RG * 160; e += 256) {
      const int g = e / 160, od = e - g * 160;
      const int o = od >> 4;
      float a = 0.0f;
#pragma unroll
      for (int i = 0; i < 16; ++i)
        a = fmaf(c_l[(g * 16 + i) * 10 + o], uhat[g][i][od], a);
      s_acc[e] += a;
    }
  }
  __syncthreads();

  for (int e = tid; e < RG * 160; e += 256) {
    const int g = e / 160, od = e - g * 160;
    s_part[((size_t)ch * N_IMG + b0 + g) * 160 + od] = s_acc[e];
  }
}

// ---------------------------------------------------------------------------
// routing pass B: reduce nchunk partials -> squash -> v, probs; vsum mode.
// ---------------------------------------------------------------------------
__global__ __launch_bounds__(192) void routing_b_kernel(
    const float* __restrict__ s_part, int nchunk, float* __restrict__ v_out,
    float* __restrict__ probs, float* __restrict__ vsum, int mode) {
  __shared__ float s_l[160];
  __shared__ float scale_l[10];
  __shared__ float len_l[10];
  const int b = blockIdx.x;
  const int t = threadIdx.x;
  if (t < 160) {
    float a = 0.0f;
    for (int ch = 0; ch < nchunk; ++ch)
      a += s_part[((size_t)ch * N_IMG + b) * 160 + t];
    s_l[t] = a;
  }
  __syncthreads();
  if (t < 10) {
    float lensq = 0.0f;
#pragma unroll
    for (int d = 0; d < 16; ++d) {
      const float xv = s_l[t * 16 + d];
      lensq = fmaf(xv, xv, lensq);
    }
    const float len = sqrtf(lensq);
    scale_l[t] = lensq / (1.0f + lensq) / len;
    len_l[t] = lensq / (1.0f + lensq);
  }
  __syncthreads();
  if (t < 160) {
    const float vv = s_l[t] * scale_l[t / 16];
    v_out[b * 160 + t] = vv;
    if (mode == 0) vsum[b * 160 + t] = vv;
    else if (mode == 1) vsum[b * 160 + t] += vv;
  }
  if (t < 10) probs[b * 10 + t] = len_l[t];
}

// ===========================================================================
extern "C" void kernel_launch(void* const* d_in, const int* in_sizes, int n_in,
                              void* d_out, int out_size, void* d_ws,
                              size_t ws_size, hipStream_t stream) {
  const float* x  = (const float*)d_in[0];
  const float* w1 = (const float*)d_in[1];
  const float* b1 = (const float*)d_in[2];
  const float* w2 = (const float*)d_in[3];
  const float* b2 = (const float*)d_in[4];
  const float* cw = (const float*)d_in[5];
  const float* bp = (const float*)d_in[6];

  float* out = (float*)d_out;
  float* v_out = out;                // [512,10,16]
  float* probs = out + N_IMG * 160;  // [512,10]

  float* base = (float*)d_ws;
  unsigned short* bph = (unsigned short*)d_ws;         // float [0, 2686976)
  unsigned short* bpl = bph + (size_t)16 * 656 * 512;  // float [2686976, 5373952)
  float* u    = base + 5373952;                        // 4718592 floats
  float* vsum = u + 4718592;                           // 81920 floats
  float* c0b  = vsum + 81920;                          // 11520 floats
  // Aliases into the bph/bpl region (dead after fused_conv):
  float* cwt = base;            // [0, 1474560)
  float* sp  = base + 1474560;  // [1474560, 4423680) — 36*512*160

  repack_b_kernel<<<dim3(16, 16), 256, 0, stream>>>(w2, bph, bpl);
  fused_conv_kernel<<<N_IMG, 512, 0, stream>>>(x, w1, b1, bph, bpl, b2, u);
  // pass 0 as GEMM (c0 is image-independent)
  c0_kernel<<<5, 256, 0, stream>>>(bp, c0b);
  repack_cw_kernel<<<1152, 160, 0, stream>>>(cw, cwt);
  gemm_s0_kernel<<<dim3(8, 36), 256, 0, stream>>>(u, cw, c0b, sp);
  routing_b_kernel<<<N_IMG, 192, 0, stream>>>(sp, 36, v_out, probs, vsum, 0);
  // passes 1..3 (4 images/block; sp region reused)
  for (int pass = 1; pass < 4; ++pass) {
    const int mode = (pass < 3) ? 1 : 2;
    routing_a_kernel<<<dim3(N_IMG / RG, 36), 256, 0, stream>>>(u, cwt, bp,
                                                               vsum, sp);
    routing_b_kernel<<<N_IMG, 192, 0, stream>>>(sp, 36, v_out, probs, vsum,
                                                mode);
  }
}

// Round 19
// 1016.538 us; speedup vs baseline: 4.4693x; 4.4693x over previous
//
#include <hip/hip_runtime.h>

// ============================================================================
// CapsuleNet forward. Round 19: REVERT to round-16 exact (1017 us, reproduced
// twice). Exploration tree closed by counters:
//  - intra-block conv/MFMA overlap: hipcc pins 128 VGPR + scratch-spills
//    (r7/r8/r14/r15: WRITE 0.46-1.4 GB).
//  - 2 blocks/CU at grid 256: impossible (grid == CU count) (r17).
//  - 2 blocks/CU via 1-img blocks at grid 512: B-traffic doubles to 11 GB,
//    L3 thrashes -> HBM-bound, MfmaUtil 8.6% (r18: FETCH 7.9 GB).
// Configuration:
//  - conv path (repack_b + fused_conv): r6 structure (592 us, VGPR 120).
//  - pass 0 as GEMM (c0 = softmax(b_prior) image-independent).
//  - passes 1-3: RG=4 routing_a (4 img/block, 2x16-cap subchunks).
// ============================================================================

#define N_IMG 512
#define RG 4  // images per routing block

typedef __attribute__((ext_vector_type(8))) short bf16x8;
typedef __attribute__((ext_vector_type(4))) float f32x4;
typedef __attribute__((ext_vector_type(4))) unsigned int u32x4;

__device__ __forceinline__ unsigned short f2bf(float v) {
  unsigned int uu = __float_as_uint(v);
  uu += 0x7FFF + ((uu >> 16) & 1);
  return (unsigned short)(uu >> 16);
}
__device__ __forceinline__ float bf2f(unsigned short h) {
  return __uint_as_float(((unsigned int)h) << 16);
}
__device__ __forceinline__ int swz16(int row) {  // byte offset of 16B A-row
  return (row ^ ((row >> 3) & 7)) << 4;
}

// ---------------------------------------------------------------------------
// repack conv2 weights w2[256co][256ci][81rs] -> B-fragment order (hi/lo).
// ---------------------------------------------------------------------------
__global__ __launch_bounds__(256) void repack_b_kernel(
    const float* __restrict__ w2, unsigned short* __restrict__ bph,
    unsigned short* __restrict__ bpl) {
  __shared__ float slab[82 * 16 * 17];  // [rs][co][ci pad 17]
  const int n = blockIdx.x, c = blockIdx.y;
  const int tid = threadIdx.x;
  for (int e = tid; e < 81 * 256; e += 256) {
    const int row = e / 81;
    const int rs = e - row * 81;
    const int co = row >> 4, ci = row & 15;
    slab[(rs * 16 + co) * 17 + ci] =
        w2[((size_t)(n * 16 + co) * 256 + c * 16 + ci) * 81 + rs];
  }
  __syncthreads();
  const int lane = tid & 63;
  const int l15 = lane & 15;
  const int lh = lane >> 5;
  const int cio8 = ((lane >> 4) & 1) * 8;
  for (int tt = tid >> 6; tt < 41; tt += 4) {
    const int rs = 2 * tt + lh;
    unsigned int hw[4], lw[4];
#pragma unroll
    for (int jp = 0; jp < 4; ++jp) {
      unsigned short h2[2], l2[2];
#pragma unroll
      for (int e = 0; e < 2; ++e) {
        const int j = jp * 2 + e;
        float v = (rs < 81) ? slab[(rs * 16 + l15) * 17 + cio8 + j] : 0.0f;
        unsigned short hh = f2bf(v);
        h2[e] = hh;
        l2[e] = f2bf(v - bf2f(hh));
      }
      hw[jp] = (unsigned int)h2[0] | ((unsigned int)h2[1] << 16);
      lw[jp] = (unsigned int)l2[0] | ((unsigned int)l2[1] << 16);
    }
    const size_t off = (((size_t)n * 656 + c * 41 + tt) * 64 + lane) * 8;
    *(u32x4*)(bph + off) = (u32x4){hw[0], hw[1], hw[2], hw[3]};
    *(u32x4*)(bpl + off) = (u32x4){lw[0], lw[1], lw[2], lw[3]};
  }
}

// ---------------------------------------------------------------------------
// transpose caps_w [1152][8][160] -> fp32 cw_t [1152][160][8].
// ---------------------------------------------------------------------------
__global__ __launch_bounds__(160) void repack_cw_kernel(
    const float* __restrict__ cw, float* __restrict__ cwt) {
  __shared__ float t[8][160];
  const int i = blockIdx.x;
  const int od = threadIdx.x;
#pragma unroll
  for (int k = 0; k < 8; ++k) t[k][od] = cw[((size_t)i * 8 + k) * 160 + od];
  __syncthreads();
  float4 o0 = {t[0][od], t[1][od], t[2][od], t[3][od]};
  float4 o1 = {t[4][od], t[5][od], t[6][od], t[7][od]};
  float4* dst = (float4*)(cwt + ((size_t)i * 160 + od) * 8);
  dst[0] = o0;
  dst[1] = o1;
}

// ---------------------------------------------------------------------------
// c0 = softmax(b_prior) per capsule (image-independent).
// ---------------------------------------------------------------------------
__global__ __launch_bounds__(256) void c0_kernel(const float* __restrict__ bp,
                                                 float* __restrict__ c0b) {
  const int i = blockIdx.x * 256 + threadIdx.x;
  if (i >= 1152) return;
  float b[10];
  float m = -1e30f;
#pragma unroll
  for (int o = 0; o < 10; ++o) {
    b[o] = bp[i * 10 + o];
    m = fmaxf(m, b[o]);
  }
  float sum = 0.0f;
#pragma unroll
  for (int o = 0; o < 10; ++o) {
    b[o] = __expf(b[o] - m);
    sum += b[o];
  }
  const float inv = 1.0f / sum;
#pragma unroll
  for (int o = 0; o < 10; ++o) c0b[i * 10 + o] = b[o] * inv;
}

// ---------------------------------------------------------------------------
// Pass-0 GEMM (r12 verbatim): s0 partials over 36 K-splits.
// ---------------------------------------------------------------------------
__global__ __launch_bounds__(256) void gemm_s0_kernel(
    const float* __restrict__ u, const float* __restrict__ cw,
    const float* __restrict__ c0b, float* __restrict__ s0p) {
  __shared__ float a_l[64 * 257];
  __shared__ float b_l[64 * 160];
  __shared__ float c0_l[320];
  const int mt = blockIdx.x;   // 0..7
  const int ks = blockIdx.y;   // 0..35
  const int m0 = mt * 64;
  const int tid = threadIdx.x;
  const int mb = tid >> 4;
  const int ob = (tid & 15) * 10;

  for (int i = tid; i < 320; i += 256) c0_l[i] = c0b[(ks * 32) * 10 + i];
  for (int idx = tid; idx < 16384; idx += 256) {
    const int m = idx >> 8, kk = idx & 255;
    a_l[m * 257 + kk] = u[(size_t)(m0 + m) * 9216 + ks * 256 + kk];
  }

  float acc[4][10];
#pragma unroll
  for (int r = 0; r < 4; ++r)
#pragma unroll
    for (int c = 0; c < 10; ++c) acc[r][c] = 0.0f;

#pragma unroll 1
  for (int kc = 0; kc < 4; ++kc) {
    __syncthreads();
    for (int idx = tid; idx < 10240; idx += 256) {
      const int kk = idx / 160, od = idx - kk * 160;
      const int kg = kc * 64 + kk;
      b_l[kk * 160 + od] = cw[((size_t)ks * 256 + kg) * 160 + od] *
                           c0_l[(kg >> 3) * 10 + (od >> 4)];
    }
    __syncthreads();
#pragma unroll 4
    for (int kk = 0; kk < 64; ++kk) {
      float a4[4];
#pragma unroll
      for (int r = 0; r < 4; ++r)
        a4[r] = a_l[(mb * 4 + r) * 257 + kc * 64 + kk];
      const float* bp_ = &b_l[kk * 160 + ob];
#pragma unroll
      for (int c = 0; c < 10; ++c) {
        const float bv = bp_[c];
#pragma unroll
        for (int r = 0; r < 4; ++r) acc[r][c] = fmaf(a4[r], bv, acc[r][c]);
      }
    }
  }

#pragma unroll
  for (int r = 0; r < 4; ++r) {
#pragma unroll
    for (int c = 0; c < 10; ++c) {
      s0p[((size_t)ks * N_IMG + m0 + mb * 4 + r) * 160 + ob + c] = acc[r][c];
    }
  }
}

// ---------------------------------------------------------------------------
// conv1 half-row worker (round-6): 10 outputs at ox' = H*10 + (0..9).
// ---------------------------------------------------------------------------
template <int H>
__device__ __forceinline__ void conv1_half(const float* __restrict__ ib,
                                           const float* __restrict__ w1l,
                                           float* __restrict__ stg, int ch,
                                           int oy, float bv1) {
  float a[10];
#pragma unroll
  for (int ox = 0; ox < 10; ++ox) a[ox] = bv1;
#pragma unroll
  for (int r = 0; r < 9; ++r) {
    float row[20];
    const float4* rp = (const float4*)&ib[(oy + r) * 28 + H * 8];
#pragma unroll
    for (int q = 0; q < 5; ++q) {
      float4 v4 = rp[q];
      row[4 * q + 0] = v4.x; row[4 * q + 1] = v4.y;
      row[4 * q + 2] = v4.z; row[4 * q + 3] = v4.w;
    }
#pragma unroll
    for (int s = 0; s < 9; ++s) {
      const float wval = w1l[ch * 81 + r * 9 + s];
#pragma unroll
      for (int ox = 0; ox < 10; ++ox)
        a[ox] = fmaf(row[ox + s + 2 * H], wval, a[ox]);
    }
  }
  float2* dst = (float2*)&stg[oy * 20 + H * 10];
#pragma unroll
  for (int q = 0; q < 5; ++q) {
    float2 v2;
    v2.x = fmaxf(a[2 * q + 0], 0.0f);
    v2.y = fmaxf(a[2 * q + 1], 0.0f);
    dst[q] = v2;
  }
}

// ---------------------------------------------------------------------------
// Fused conv1 -> hi/lo A (swizzled) -> MFMA conv2 (k-split, depth-2 B
// prefetch) -> squash.  VERBATIM round 6/9/16 (592 us, VGPR 120, no spill).
// ---------------------------------------------------------------------------
__global__ __launch_bounds__(512, 1) void fused_conv_kernel(
    const float* __restrict__ x, const float* __restrict__ w1,
    const float* __restrict__ b1, const unsigned short* __restrict__ bph,
    const unsigned short* __restrict__ bpl, const float* __restrict__ b2,
    float* __restrict__ u) {
  __shared__ __align__(16) char smem[115008];
  float* stg = (float*)(smem + 51776);   // [2][16][404]
  float* img = (float*)(smem + 103488);  // [2][784]
  float* w1l = (float*)(smem + 109760);  // [16*81]
  float* b1l = (float*)(smem + 114944);  // [16]
  float* mrg = (float*)smem;
  float* sq = (float*)smem;

  const int bp2 = blockIdx.x;
  const int tid = threadIdx.x;
  const int wid = tid >> 6;
  const int g = wid & 3;
  const int kpar = wid >> 2;
  const int lane = tid & 63;
  const int l15 = lane & 15;
  const int lq4 = lane >> 4;
  const int lqb = lq4 & 1;
  const int lh = lane >> 5;

  int rowb[5];
  bool okm[5];
#pragma unroll
  for (int mt = 0; mt < 5; ++mt) {
    const int m = mt * 16 + l15;
    okm[mt] = (m < 72);
    const int mm = okm[mt] ? m : 0;
    const int im = (mm >= 36) ? 1 : 0;
    const int p = mm - 36 * im;
    const int oy = p / 6, ox = p - 6 * oy;
    rowb[mt] = im * 400 + 40 * oy + 2 * ox;
  }

  for (int i = tid; i < 1568; i += 512) img[i] = x[bp2 * 1568 + i];
  if (tid < 16) {  // zero pad-slot 800 (swz 804) in all 4 arrays
    *(int*)(smem + (tid >> 2) * 12944 + 804 * 16 + (tid & 3) * 4) = 0;
  }

  f32x4 acc[5][4];
#pragma unroll
  for (int mt = 0; mt < 5; ++mt)
#pragma unroll
    for (int nn = 0; nn < 4; ++nn) acc[mt][nn] = (f32x4){0.f, 0.f, 0.f, 0.f};

  const char* hbase = smem + lqb * 12944;
  const char* lbase = smem + 25888 + lqb * 12944;
  const int tt0 = kpar ? 21 : 0;
  const int tt1 = kpar ? 41 : 21;
  const int nk = tt1 - tt0;

#define MFMA_STEP(CBH, CBL, J, DOPF)                                       \
  {                                                                        \
    const int rs_ = 2 * (tt0 + (J)) + lh;                                  \
    const int r_ = (rs_ * 57) >> 9;                                        \
    const int s_ = rs_ - 9 * r_;                                           \
    const int rs20_ = 20 * r_ + s_;                                        \
    const bool okrs_ = (rs_ <= 80);                                        \
    bf16x8 ah[5], al[5];                                                   \
    _Pragma("unroll") for (int mt = 0; mt < 5; ++mt) {                     \
      const int row_ = (okm[mt] && okrs_) ? (rowb[mt] + rs20_) : 800;      \
      const int ad_ = swz16(row_);                                         \
      ah[mt] = *(const bf16x8*)(hbase + ad_);                              \
      al[mt] = *(const bf16x8*)(lbase + ad_);                              \
    }                                                                      \
    _Pragma("unroll") for (int mt = 0; mt < 5; ++mt) {                     \
      _Pragma("unroll") for (int nn = 0; nn < 4; ++nn) {                   \
        acc[mt][nn] = __builtin_amdgcn_mfma_f32_16x16x32_bf16(             \
            al[mt], CBH[nn], acc[mt][nn], 0, 0, 0);                        \
        acc[mt][nn] = __builtin_amdgcn_mfma_f32_16x16x32_bf16(             \
            ah[mt], CBL[nn], acc[mt][nn], 0, 0, 0);                        \
        acc[mt][nn] = __builtin_amdgcn_mfma_f32_16x16x32_bf16(             \
            ah[mt], CBH[nn], acc[mt][nn], 0, 0, 0);                        \
      }                                                                    \
    }                                                                      \
    if ((DOPF) && (J) + 2 < nk) {                                          \
      _Pragma("unroll") for (int nn = 0; nn < 4; ++nn) {                   \
        CBH[nn] = *(const bf16x8*)(pb[nn] + (size_t)((J) + 2) * 512);      \
        CBL[nn] = *(const bf16x8*)(pl[nn] + (size_t)((J) + 2) * 512);      \
      }                                                                    \
    }                                                                      \
  }

#pragma unroll 1
  for (int c = 0; c < 16; ++c) {
    const unsigned short* pb[4];
    const unsigned short* pl[4];
#pragma unroll
    for (int nn = 0; nn < 4; ++nn) {
      const size_t base =
          ((size_t)(g * 4 + nn) * 656 + c * 41 + tt0) * 512 + lane * 8;
      pb[nn] = bph + base;
      pl[nn] = bpl + base;
    }
    bf16x8 cbh0[4], cbl0[4], cbh1[4], cbl1[4];
#pragma unroll
    for (int nn = 0; nn < 4; ++nn) {
      cbh0[nn] = *(const bf16x8*)(pb[nn]);
      cbl0[nn] = *(const bf16x8*)(pl[nn]);
      cbh1[nn] = *(const bf16x8*)(pb[nn] + 512);
      cbl1[nn] = *(const bf16x8*)(pl[nn] + 512);
    }

    __syncthreads();
    for (int i = tid; i < 1296; i += 512) w1l[i] = w1[c * 1296 + i];
    if (tid < 16) b1l[tid] = b1[c * 16 + tid];
    __syncthreads();

    for (int t = tid; t < 1280; t += 512) {
      const int half = (t >= 640) ? 1 : 0;
      const int rest = t - half * 640;
      const int ig = rest / 320;
      const int r2 = rest - ig * 320;
      const int ch = r2 & 15;
      const int oy = r2 >> 4;
      const float* ib = &img[ig * 784];
      float* sb = &stg[(ig * 16 + ch) * 404];
      const float bv1 = b1l[ch];
      if (half == 0)
        conv1_half<0>(ib, w1l, sb, ch, oy, bv1);
      else
        conv1_half<1>(ib, w1l, sb, ch, oy, bv1);
    }
    __syncthreads();

    for (int t = tid; t < 800; t += 512) {
      const int ig = t / 400;
      const int pos = t - ig * 400;
      const int ad = swz16(t);
      unsigned int hw[8], lw[8];
#pragma unroll
      for (int jp = 0; jp < 8; ++jp) {
        unsigned short h2[2], l2[2];
#pragma unroll
        for (int e = 0; e < 2; ++e) {
          const float v = stg[(ig * 16 + jp * 2 + e) * 404 + pos];
          const unsigned short hh = f2bf(v);
          h2[e] = hh;
          l2[e] = f2bf(v - bf2f(hh));
        }
        hw[jp] = (unsigned int)h2[0] | ((unsigned int)h2[1] << 16);
        lw[jp] = (unsigned int)l2[0] | ((unsigned int)l2[1] << 16);
      }
      *(u32x4*)(smem + ad) = (u32x4){hw[0], hw[1], hw[2], hw[3]};
      *(u32x4*)(smem + 12944 + ad) = (u32x4){hw[4], hw[5], hw[6], hw[7]};
      *(u32x4*)(smem + 25888 + ad) = (u32x4){lw[0], lw[1], lw[2], lw[3]};
      *(u32x4*)(smem + 38832 + ad) = (u32x4){lw[4], lw[5], lw[6], lw[7]};
    }
    __syncthreads();

    int j = 0;
#pragma unroll 1
    for (; j + 1 < nk; j += 2) {
      MFMA_STEP(cbh0, cbl0, j, 1);
      MFMA_STEP(cbh1, cbl1, j + 1, 1);
    }
    if (j < nk) MFMA_STEP(cbh0, cbl0, j, 0);
  }
#undef MFMA_STEP

  __syncthreads();
  if (kpar == 1) {
#pragma unroll
    for (int mt = 0; mt < 5; ++mt)
#pragma unroll
      for (int nn = 0; nn < 4; ++nn)
        *(f32x4*)(mrg + ((((g * 5 + mt) * 4 + nn) * 64 + lane) << 2)) =
            acc[mt][nn];
  }
  __syncthreads();
  if (kpar == 0) {
#pragma unroll
    for (int mt = 0; mt < 5; ++mt)
#pragma unroll
      for (int nn = 0; nn < 4; ++nn)
        acc[mt][nn] +=
            *(const f32x4*)(mrg + ((((g * 5 + mt) * 4 + nn) * 64 + lane) << 2));
  }
  __syncthreads();
  if (kpar == 0) {
    float b2v[4];
#pragma unroll
    for (int nn = 0; nn < 4; ++nn) b2v[nn] = b2[(g * 4 + nn) * 16 + l15];
#pragma unroll
    for (int mt = 0; mt < 5; ++mt) {
#pragma unroll
      for (int i = 0; i < 4; ++i) {
        const int m = mt * 16 + lq4 * 4 + i;
        if (m < 72) {
          const int im = (m >= 36) ? 1 : 0;
          const int p36 = m - 36 * im;
#pragma unroll
          for (int nn = 0; nn < 4; ++nn) {
            sq[(im * 256 + (g * 4 + nn) * 16 + l15) * 36 + p36] =
                acc[mt][nn][i] + b2v[nn];
          }
        }
      }
    }
  }
  __syncthreads();

  for (int i = tid; i < 2304; i += 512) {
    const int ig = i / 1152;
    const int cap = i - ig * 1152;
    const int gg = cap / 36, yx = cap - 36 * gg;
    float vals[8];
    float lensq = 0.0f;
#pragma unroll
    for (int d = 0; d < 8; ++d) {
      vals[d] = sq[(ig * 256 + gg * 8 + d) * 36 + yx];
      lensq = fmaf(vals[d], vals[d], lensq);
    }
    const float len = sqrtf(lensq);
    const float scale = lensq / (1.0f + lensq) / len;
    float4* dst = (float4*)(u + ((size_t)(bp2 * 2 + ig) * 1152 + cap) * 8);
    float4 lo4, hi4;
    lo4.x = vals[0] * scale; lo4.y = vals[1] * scale;
    lo4.z = vals[2] * scale; lo4.w = vals[3] * scale;
    hi4.x = vals[4] * scale; hi4.y = vals[5] * scale;
    hi4.z = vals[6] * scale; hi4.w = vals[7] * scale;
    dst[0] = lo4; dst[1] = hi4;
  }
}

// ---------------------------------------------------------------------------
// routing pass A (passes 1-3, r13 verbatim): 4 images/block, 32-cap chunk as
// 2x16 subchunks; each cwt read serves 4 images (L2 traffic /4).
// ---------------------------------------------------------------------------
__global__ __launch_bounds__(256) void routing_a_kernel(
    const float* __restrict__ u, const float* __restrict__ cwt,
    const float* __restrict__ b_prior, const float* __restrict__ vsum,
    float* __restrict__ s_part) {
  __shared__ float u_l[RG * 16 * 8];
  __shared__ float uhat[RG][16][161];
  __shared__ float v_l[RG * 160];
  __shared__ float bp_l[32 * 10];
  __shared__ float c_l[RG * 16 * 10];
  __shared__ float s_acc[RG * 160];

  const int gb = blockIdx.x;  // image group (4 images)
  const int ch = blockIdx.y;  // 32-cap chunk (0..35)
  const int cap0 = ch * 32;
  const int b0 = gb * RG;
  const int tid = threadIdx.x;

  for (int i = tid; i < RG * 160; i += 256) {
    const int g = i / 160, od = i - g * 160;
    v_l[i] = vsum[(b0 + g) * 160 + od];
    s_acc[i] = 0.0f;
  }
  for (int i = tid; i < 320; i += 256) bp_l[i] = b_prior[cap0 * 10 + i];

#pragma unroll 1
  for (int cc = 0; cc < 2; ++cc) {
    const int c16 = cap0 + cc * 16;
    __syncthreads();
    for (int i = tid; i < RG * 128; i += 256) {
      const int g = i >> 7, off = i & 127;
      u_l[g * 128 + off] = u[((size_t)(b0 + g) * 1152 + c16) * 8 + off];
    }
    __syncthreads();

    for (int e = tid; e < 2560; e += 256) {
      const int i = e / 160, od = e - i * 160;
      const float4* wp =
          (const float4*)(cwt + ((size_t)(c16 + i) * 160 + od) * 8);
      const float4 wa = wp[0], wb = wp[1];
#pragma unroll
      for (int g = 0; g < RG; ++g) {
        const float* up = &u_l[(g * 16 + i) * 8];
        float a = up[0] * wa.x;
        a = fmaf(up[1], wa.y, a);
        a = fmaf(up[2], wa.z, a);
        a = fmaf(up[3], wa.w, a);
        a = fmaf(up[4], wb.x, a);
        a = fmaf(up[5], wb.y, a);
        a = fmaf(up[6], wb.z, a);
        a = fmaf(up[7], wb.w, a);
        uhat[g][i][od] = a;
      }
    }
    __syncthreads();

    for (int e = tid; e < RG * 160; e += 256) {
      const int g = e / 160;
      const int r = e - g * 160;
      const int i = r / 10, o = r - i * 10;
      float agg = 0.0f;
#pragma unroll
      for (int d = 0; d < 16; ++d)
        agg = fmaf(uhat[g][i][o * 16 + d], v_l[g * 160 + o * 16 + d], agg);
      c_l[e] = bp_l[(cc * 16 + i) * 10 + o] + agg;
    }
    __syncthreads();

    if (tid < RG * 16) {
      const int g = tid >> 4, i = tid & 15;
      float bb[10];
      float m = -1e30f;
#pragma unroll
      for (int o = 0; o < 10; ++o) {
        bb[o] = c_l[(g * 16 + i) * 10 + o];
        m = fmaxf(m, bb[o]);
      }
      float sum = 0.0f;
#pragma unroll
      for (int o = 0; o < 10; ++o) {
        bb[o] = __expf(bb[o] - m);
        sum += bb[o];
      }
      const float inv = 1.0f / sum;
#pragma unroll
      for (int o = 0; o < 10; ++o) c_l[(g * 16 + i) * 10 + o] = bb[o] * inv;
    }
    __syncthreads();

    for (int e = tid; e < RG * 160; e += 256) {
      const int g = e / 160, od = e - g * 160;
      const int o = od >> 4;
      float a = 0.0f;
#pragma unroll
      for (int i = 0; i < 16; ++i)
        a = fmaf(c_l[(g * 16 + i) * 10 + o], uhat[g][i][od], a);
      s_acc[e] += a;
    }
  }
  __syncthreads();

  for (int e = tid; e < RG * 160; e += 256) {
    const int g = e / 160, od = e - g * 160;
    s_part[((size_t)ch * N_IMG + b0 + g) * 160 + od] = s_acc[e];
  }
}

// ---------------------------------------------------------------------------
// routing pass B: reduce nchunk partials -> squash -> v, probs; vsum mode.
// ---------------------------------------------------------------------------
__global__ __launch_bounds__(192) void routing_b_kernel(
    const float* __restrict__ s_part, int nchunk, float* __restrict__ v_out,
    float* __restrict__ probs, float* __restrict__ vsum, int mode) {
  __shared__ float s_l[160];
  __shared__ float scale_l[10];
  __shared__ float len_l[10];
  const int b = blockIdx.x;
  const int t = threadIdx.x;
  if (t < 160) {
    float a = 0.0f;
    for (int ch = 0; ch < nchunk; ++ch)
      a += s_part[((size_t)ch * N_IMG + b) * 160 + t];
    s_l[t] = a;
  }
  __syncthreads();
  if (t < 10) {
    float lensq = 0.0f;
#pragma unroll
    for (int d = 0; d < 16; ++d) {
      const float xv = s_l[t * 16 + d];
      lensq = fmaf(xv, xv, lensq);
    }
    const float len = sqrtf(lensq);
    scale_l[t] = lensq / (1.0f + lensq) / len;
    len_l[t] = lensq / (1.0f + lensq);
  }
  __syncthreads();
  if (t < 160) {
    const float vv = s_l[t] * scale_l[t / 16];
    v_out[b * 160 + t] = vv;
    if (mode == 0) vsum[b * 160 + t] = vv;
    else if (mode == 1) vsum[b * 160 + t] += vv;
  }
  if (t < 10) probs[b * 10 + t] = len_l[t];
}

// ===========================================================================
extern "C" void kernel_launch(void* const* d_in, const int* in_sizes, int n_in,
                              void* d_out, int out_size, void* d_ws,
                              size_t ws_size, hipStream_t stream) {
  const float* x  = (const float*)d_in[0];
  const float* w1 = (const float*)d_in[1];
  const float* b1 = (const float*)d_in[2];
  const float* w2 = (const float*)d_in[3];
  const float* b2 = (const float*)d_in[4];
  const float* cw = (const float*)d_in[5];
  const float* bp = (const float*)d_in[6];

  float* out = (float*)d_out;
  float* v_out = out;                // [512,10,16]
  float* probs = out + N_IMG * 160;  // [512,10]

  float* base = (float*)d_ws;
  unsigned short* bph = (unsigned short*)d_ws;         // float [0, 2686976)
  unsigned short* bpl = bph + (size_t)16 * 656 * 512;  // float [2686976, 5373952)
  float* u    = base + 5373952;                        // 4718592 floats
  float* vsum = u + 4718592;                           // 81920 floats
  float* c0b  = vsum + 81920;                          // 11520 floats
  // Aliases into the bph/bpl region (dead after fused_conv):
  float* cwt = base;            // [0, 1474560)
  float* sp  = base + 1474560;  // [1474560, 4423680) — 36*512*160

  repack_b_kernel<<<dim3(16, 16), 256, 0, stream>>>(w2, bph, bpl);
  fused_conv_kernel<<<256, 512, 0, stream>>>(x, w1, b1, bph, bpl, b2, u);
  // pass 0 as GEMM (c0 is image-independent)
  c0_kernel<<<5, 256, 0, stream>>>(bp, c0b);
  repack_cw_kernel<<<1152, 160, 0, stream>>>(cw, cwt);
  gemm_s0_kernel<<<dim3(8, 36), 256, 0, stream>>>(u, cw, c0b, sp);
  routing_b_kernel<<<N_IMG, 192, 0, stream>>>(sp, 36, v_out, probs, vsum, 0);
  // passes 1..3 (4 images/block; sp region reused)
  for (int pass = 1; pass < 4; ++pass) {
    const int mode = (pass < 3) ? 1 : 2;
    routing_a_kernel<<<dim3(N_IMG / RG, 36), 256, 0, stream>>>(u, cwt, bp,
                                                               vsum, sp);
    routing_b_kernel<<<N_IMG, 192, 0, stream>>>(sp, 36, v_out, probs, vsum,
                                                mode);
  }
}